// Round 3
// baseline (1484.286 us; speedup 1.0000x reference)
//
#include <hip/hip_runtime.h>
#include <hip/hip_cooperative_groups.h>

namespace cg = cooperative_groups;

#define W 1024
#define H 1024
#define SP 1032                      // padded row stride (floats)
#define HP 1026                      // padded rows (1 halo top/bottom)
#define FR ((size_t)SP * (size_t)HP) // floats per padded buffer
#define NPIX (H * W)

__device__ __forceinline__ float frcp_(float v) { return __builtin_amdgcn_rcpf(v); }
__device__ __forceinline__ float sigm_(float v) { return frcp_(1.0f + __expf(-v)); }
__device__ __forceinline__ float tanh_(float v) {
    return 1.0f - 2.0f * frcp_(1.0f + __expf(2.0f * v));
}

// Pads the 20 input frames into ws[0..20FR) and zeroes h0,h1,h2 in [20FR,23FR).
__global__ __launch_bounds__(256) void init_pad(const float* __restrict__ data,
                                                float* __restrict__ ws) {
    const int R4 = SP / 4;                 // 258 float4 per padded row
    const size_t n4_fr  = 20 * (FR / 4);
    const size_t n4_tot = 23 * (FR / 4);
    size_t i = (size_t)blockIdx.x * blockDim.x + threadIdx.x;
    const size_t stride = (size_t)gridDim.x * blockDim.x;
    float4* w4 = (float4*)ws;
    for (; i < n4_tot; i += stride) {
        float4 v = make_float4(0.f, 0.f, 0.f, 0.f);
        if (i < n4_fr) {
            size_t f = i / (size_t)(HP * R4);
            int rem = (int)(i - f * (size_t)(HP * R4));
            int pr  = rem / R4;
            int k4  = rem - pr * R4;
            if (pr >= 1 && pr <= H && k4 >= 1 && k4 <= 256) {
                v = *(const float4*)(data + f * (size_t)NPIX +
                                     (size_t)(pr - 1) * W + (size_t)(k4 - 1) * 4);
            }
        }
        w4[i] = v;
    }
}

// Accumulate one input channel's 3x3 conv into acc[4][4].
// s = channel base + this thread's padded-pixel offset. wofs: 0 (x-ch), 9 (h-ch).
__device__ __forceinline__ void conv_ch(const float* __restrict__ s,
                                        const float* __restrict__ wg, int wofs,
                                        float acc[4][4]) {
#pragma unroll
    for (int dy = 0; dy < 3; ++dy) {
        const float* p = s + (dy - 1) * (int)SP;
        const float4 m = *(const float4*)p;
        const float in6[6] = {p[-1], m.x, m.y, m.z, m.w, p[4]};
#pragma unroll
        for (int co = 0; co < 4; ++co) {
            const float w0 = wg[co * 18 + wofs + dy * 3 + 0];
            const float w1 = wg[co * 18 + wofs + dy * 3 + 1];
            const float w2 = wg[co * 18 + wofs + dy * 3 + 2];
#pragma unroll
            for (int j = 0; j < 4; ++j)
                acc[co][j] += w0 * in6[j] + w1 * in6[j + 1] + w2 * in6[j + 2];
        }
    }
}

// LSTM pointwise: updates cc[] in place, returns h as float4. Gate order i,f,o,g.
__device__ __forceinline__ float4 pointwise(const float acc[4][4], float cc[4]) {
    float hh[4];
#pragma unroll
    for (int j = 0; j < 4; ++j) {
        const float gi = sigm_(acc[0][j]);
        const float gf = sigm_(acc[1][j]);
        const float go = sigm_(acc[2][j]);
        const float gg = tanh_(acc[3][j]);
        const float cn = gf * cc[j] + gi * gg;
        cc[j] = cn;
        hh[j] = go * tanh_(cn);
    }
    return make_float4(hh[0], hh[1], hh[2], hh[3]);
}

// One persistent cooperative kernel: 20 encoder + 20 decoder steps,
// grid.sync() between steps. c-state in registers the whole time.
// 256 blocks x 1024 threads: block owns 4 rows, thread owns 4 px of one row.
__global__ __launch_bounds__(1024, 4) void lstm_seq(
    const float* __restrict__ xpad,  // 20 padded frames
    float* __restrict__ h0, float* __restrict__ h1, float* __restrict__ h2,
    float* __restrict__ dout,
    const float* __restrict__ ew, const float* __restrict__ eb,
    const float* __restrict__ dw, const float* __restrict__ db_)
{
    cg::grid_group grid = cg::this_grid();
    const int tid = threadIdx.x;
    const int r = blockIdx.x * 4 + (tid >> 8);   // image row
    const int k = tid & 255;                      // 4-px group in row
    const size_t base = (size_t)(r + 1) * SP + (4 + 4 * k);

    // ---------------- encoder: h ping-pongs h0<->h1, c in registers ----------
    float cc[4] = {0.f, 0.f, 0.f, 0.f};
    {
        float* hp = h0;   // only read when t>0
        float* hn = h1;
        for (int t = 0; t < 20; ++t) {
            float acc[4][4];
#pragma unroll
            for (int co = 0; co < 4; ++co) {
                const float bb = eb[co];
#pragma unroll
                for (int j = 0; j < 4; ++j) acc[co][j] = bb;
            }
            conv_ch(xpad + (size_t)t * FR + base, ew, 0, acc);
            if (t > 0) conv_ch(hp + base, ew, 9, acc);
            const float4 hv = pointwise(acc, cc);
            *(float4*)(hn + base) = hv;
            grid.sync();
            float* tmp = hp; hp = hn; hn = tmp;
        }
    }
    // 20 steps (even): final encoder h is in h0, halos zero (never written).

    // ---------------- decoder: constant input h0 --------------------------
    // Precompute the x-channel conv + bias once; reuse for all 20 steps.
    float accx[4][4];
#pragma unroll
    for (int co = 0; co < 4; ++co) {
        const float bb = db_[co];
#pragma unroll
        for (int j = 0; j < 4; ++j) accx[co][j] = bb;
    }
    conv_ch(h0 + base, dw, 0, accx);

    float cd[4] = {0.f, 0.f, 0.f, 0.f};
    float* hp = h2;   // content unused at t=0
    float* hn = h1;
    for (int t = 0; t < 20; ++t) {
        float acc[4][4];
#pragma unroll
        for (int co = 0; co < 4; ++co)
#pragma unroll
            for (int j = 0; j < 4; ++j) acc[co][j] = accx[co][j];
        if (t > 0) conv_ch(hp + base, dw, 9, acc);
        const float4 hv = pointwise(acc, cd);
        if (t == 19) {
            *(float4*)(dout + (size_t)r * W + 4 * k) = hv;
        } else {
            *(float4*)(hn + base) = hv;
            grid.sync();
            float* tmp = hp; hp = hn; hn = tmp;
        }
    }
}

extern "C" void kernel_launch(void* const* d_in, const int* in_sizes, int n_in,
                              void* d_out, int out_size, void* d_ws, size_t ws_size,
                              hipStream_t stream) {
    const float* data  = (const float*)d_in[0];  // [20,1,1,1024,1024]
    const float* enc_w = (const float*)d_in[1];  // [4,2,3,3]
    const float* enc_b = (const float*)d_in[2];  // [4]
    const float* dec_w = (const float*)d_in[3];
    const float* dec_b = (const float*)d_in[4];
    // d_in[5..7] = epoch(0), T_en(20), T_de(20): constant device scalars;
    // loop counts hardcoded (host can't read device memory under capture).

    float* ws   = (float*)d_ws;
    const float* xpad = ws;          // 20 padded frames
    float* h0 = ws + 20 * FR;
    float* h1 = ws + 21 * FR;
    float* h2 = ws + 22 * FR;
    float* dout = (float*)d_out;
    // ws use: 23*FR*4 B ~= 97 MB

    init_pad<<<2048, 256, 0, stream>>>(data, ws);

    void* args[] = {
        (void*)&xpad, (void*)&h0, (void*)&h1, (void*)&h2, (void*)&dout,
        (void*)&enc_w, (void*)&enc_b, (void*)&dec_w, (void*)&dec_b
    };
    hipLaunchCooperativeKernel((void*)lstm_seq, dim3(256), dim3(1024),
                               args, 0, stream);
}

// Round 4
// 427.573 us; speedup vs baseline: 3.4714x; 3.4714x over previous
//
#include <hip/hip_runtime.h>

#define W 1024
#define H 1024
#define PAD 8                         // zero-pad width around frames/state
#define XS 1040                       // padded row stride (floats)
#define FR2 ((size_t)XS * (size_t)XS) // floats per padded buffer
#define NPIX (H * W)
#define LC 80                         // local tile width (floats), cols c0-8..c0+71
#define LRW 74                        // local tile rows, rows r0-5..r0+68
#define NB 512                        // threads per block

__device__ __forceinline__ float frcp_(float v) { return __builtin_amdgcn_rcpf(v); }
__device__ __forceinline__ float sigm_(float v) { return frcp_(1.0f + __expf(-v)); }
__device__ __forceinline__ float tanh_(float v) {
    return 1.0f - 2.0f * frcp_(1.0f + __expf(2.0f * v));
}

// Pads the 20 input frames into ws[0..20FR2) (interior copy, 8-wide zero halo)
// and zeroes the 5 state buffers ws[20FR2..25FR2).
__global__ __launch_bounds__(256) void init_pad(const float* __restrict__ data,
                                                float* __restrict__ ws) {
    const int R4 = XS / 4;                 // 260 float4 per padded row
    const size_t n4_fr  = 20 * (FR2 / 4);
    const size_t n4_tot = 25 * (FR2 / 4);
    size_t i = (size_t)blockIdx.x * blockDim.x + threadIdx.x;
    const size_t stride = (size_t)gridDim.x * blockDim.x;
    float4* w4 = (float4*)ws;
    for (; i < n4_tot; i += stride) {
        float4 v = make_float4(0.f, 0.f, 0.f, 0.f);
        if (i < n4_fr) {
            size_t f = i / (size_t)(XS * R4);
            int rem = (int)(i - f * (size_t)(XS * R4));
            int pr  = rem / R4;            // padded row
            int k4  = rem - pr * R4;       // float4 index in row
            if (pr >= PAD && pr < PAD + H && k4 >= 2 && k4 < 2 + W / 4) {
                v = *(const float4*)(data + f * (size_t)NPIX +
                                     (size_t)(pr - PAD) * W + (4 * k4 - PAD));
            }
        }
        w4[i] = v;
    }
}

// 5 fused conv-LSTM steps. 256 blocks (16x16 tiles of 64x64 px), 512 threads.
// Local tile in LDS: h (in-place, two-phase update) + c, 74 rows x 80 cols.
// Step i (1..5) computes rows [i,74-i), col-groups j in [1,19); fresh-region
// shrink matches stencil pollution speed, so interior 64x64 is exact at step 5.
// x channel read from global padded frames (xstep=FR2 encoder, 0 decoder).
__global__ __launch_bounds__(NB) void fused5(
    const float* __restrict__ xbase, size_t xstep,
    const float* __restrict__ hin, const float* __restrict__ cin,
    float* __restrict__ hout, float* __restrict__ cout_,
    const float* __restrict__ wg, const float* __restrict__ bg,
    float* __restrict__ dout, int zero_init)
{
    __shared__ float hT[LRW * LC];
    __shared__ float cT[LRW * LC];
    const int tid = threadIdx.x;
    const int bx = blockIdx.x & 15, by = blockIdx.x >> 4;
    const int c0 = bx * 64, r0 = by * 64;
    // local (lr, col-group j): global row gr = r0-5+lr, col gc = c0-8+4j
    // padded-buffer addr = (gr+PAD)*XS + (gc+PAD) = (r0+3+lr)*XS + (c0+4j)

    // ---- initial tile load (or zero) ----
    for (int idx = tid; idx < LRW * (LC / 4); idx += NB) {
        int lr = idx / (LC / 4);
        int j  = idx - lr * (LC / 4);
        float4 hv = make_float4(0.f, 0.f, 0.f, 0.f);
        float4 cv = hv;
        if (!zero_init) {
            size_t o = (size_t)(r0 + 3 + lr) * XS + (c0 + 4 * j);
            hv = *(const float4*)(hin + o);
            cv = *(const float4*)(cin + o);
        }
        *(float4*)(hT + lr * LC + 4 * j) = hv;
        *(float4*)(cT + lr * LC + 4 * j) = cv;
    }
    __syncthreads();

#pragma unroll
    for (int i = 1; i <= 5; ++i) {
        const float* xf = xbase + (size_t)(i - 1) * xstep;
        const int G = (LRW - 2 * i) * 18;
        float4 hsave[3];
        int    hofs[3];
        int ng = 0;
        for (int g = tid; g < G; g += NB) {
            const int q  = g / 18;
            const int lr = i + q;
            const int j  = 1 + (g - q * 18);
            const int lb = lr * LC + 4 * j;

            float acc[4][4];
#pragma unroll
            for (int co = 0; co < 4; ++co) {
                const float bb = bg[co];
#pragma unroll
                for (int e = 0; e < 4; ++e) acc[co][e] = bb;
            }
            // x channel (global, padded)
            {
                const float* p = xf + (size_t)(r0 + 2 + lr) * XS + (c0 + 4 * j);
#pragma unroll
                for (int dy = 0; dy < 3; ++dy) {
                    const float4 m = *(const float4*)p;
                    const float in6[6] = {p[-1], m.x, m.y, m.z, m.w, p[4]};
#pragma unroll
                    for (int co = 0; co < 4; ++co) {
                        const float w0 = wg[co * 18 + dy * 3 + 0];
                        const float w1 = wg[co * 18 + dy * 3 + 1];
                        const float w2 = wg[co * 18 + dy * 3 + 2];
#pragma unroll
                        for (int e = 0; e < 4; ++e)
                            acc[co][e] += w0 * in6[e] + w1 * in6[e+1] + w2 * in6[e+2];
                    }
                    p += XS;
                }
            }
            // h channel (LDS)
            {
                const float* p = hT + lb - LC;
#pragma unroll
                for (int dy = 0; dy < 3; ++dy) {
                    const float4 m = *(const float4*)p;
                    const float in6[6] = {p[-1], m.x, m.y, m.z, m.w, p[4]};
#pragma unroll
                    for (int co = 0; co < 4; ++co) {
                        const float w0 = wg[co * 18 + 9 + dy * 3 + 0];
                        const float w1 = wg[co * 18 + 9 + dy * 3 + 1];
                        const float w2 = wg[co * 18 + 9 + dy * 3 + 2];
#pragma unroll
                        for (int e = 0; e < 4; ++e)
                            acc[co][e] += w0 * in6[e] + w1 * in6[e+1] + w2 * in6[e+2];
                    }
                    p += LC;
                }
            }
            // pointwise LSTM + zero-mask outside the image
            const float4 cv = *(const float4*)(cT + lb);
            float cc[4] = {cv.x, cv.y, cv.z, cv.w};
            float hh[4];
#pragma unroll
            for (int e = 0; e < 4; ++e) {
                const float gi = sigm_(acc[0][e]);
                const float gf = sigm_(acc[1][e]);
                const float go = sigm_(acc[2][e]);
                const float gg = tanh_(acc[3][e]);
                const float cn = gf * cc[e] + gi * gg;
                cc[e] = cn;
                hh[e] = go * tanh_(cn);
            }
            const int gr = r0 - 5 + lr;
            const int gc = c0 - 8 + 4 * j;
            const bool rok = (unsigned)gr < (unsigned)H;
#pragma unroll
            for (int e = 0; e < 4; ++e)
                if (!(rok && (unsigned)(gc + e) < (unsigned)W)) hh[e] = 0.f;

            *(float4*)(cT + lb) = make_float4(cc[0], cc[1], cc[2], cc[3]);
            hsave[ng] = make_float4(hh[0], hh[1], hh[2], hh[3]);
            hofs[ng]  = lb;
            ++ng;
        }
        __syncthreads();             // all reads of h_{i-1} done
        for (int k2 = 0; k2 < ng; ++k2)
            *(float4*)(hT + hofs[k2]) = hsave[k2];
        __syncthreads();             // h_i visible
    }

    // ---- write interior 64x64 (h,c) or final output ----
    for (int idx = tid; idx < 64 * 16; idx += NB) {
        const int lr = 5 + (idx >> 4);
        const int j  = 2 + (idx & 15);
        const int lb = lr * LC + 4 * j;
        const float4 hv = *(const float4*)(hT + lb);
        const int gr = r0 + (idx >> 4);
        const int gc = c0 + 4 * (idx & 15);
        if (dout) {
            *(float4*)(dout + (size_t)gr * W + gc) = hv;
        } else {
            const size_t o = (size_t)(gr + PAD) * XS + (gc + PAD);
            *(float4*)(hout + o)  = hv;
            *(float4*)(cout_ + o) = *(const float4*)(cT + lb);
        }
    }
}

extern "C" void kernel_launch(void* const* d_in, const int* in_sizes, int n_in,
                              void* d_out, int out_size, void* d_ws, size_t ws_size,
                              hipStream_t stream) {
    const float* data  = (const float*)d_in[0];  // [20,1,1,1024,1024]
    const float* enc_w = (const float*)d_in[1];  // [4,2,3,3]
    const float* enc_b = (const float*)d_in[2];  // [4]
    const float* dec_w = (const float*)d_in[3];
    const float* dec_b = (const float*)d_in[4];
    // d_in[5..7] = epoch(0), T_en(20), T_de(20): constant device scalars;
    // loop counts hardcoded (host can't read device memory under capture).

    float* ws   = (float*)d_ws;
    float* xpad = ws;                 // 20 padded frames
    float* hE0  = ws + 20 * FR2;
    float* hE1  = ws + 21 * FR2;
    float* cE0  = ws + 22 * FR2;
    float* cE1  = ws + 23 * FR2;
    float* hX   = ws + 24 * FR2;
    float* dout = (float*)d_out;
    // ws use: 25*FR2*4 B ~= 108 MB

    init_pad<<<2048, 256, 0, stream>>>(data, ws);

    dim3 blk(NB), grd(256);
    // encoder: 4 launches x 5 steps; state ping-pongs (hE0,cE0)<->(hE1,cE1)
    fused5<<<grd, blk, 0, stream>>>(xpad,            FR2, hE0, cE0, hE1, cE1,
                                    enc_w, enc_b, nullptr, 1);
    fused5<<<grd, blk, 0, stream>>>(xpad +  5 * FR2, FR2, hE1, cE1, hE0, cE0,
                                    enc_w, enc_b, nullptr, 0);
    fused5<<<grd, blk, 0, stream>>>(xpad + 10 * FR2, FR2, hE0, cE0, hE1, cE1,
                                    enc_w, enc_b, nullptr, 0);
    fused5<<<grd, blk, 0, stream>>>(xpad + 15 * FR2, FR2, hE1, cE1, hE0, cE0,
                                    enc_w, enc_b, nullptr, 0);
    // final encoder h in hE0 (= constant decoder input; its zero halo ring
    // reproduces SAME zero-padding).
    fused5<<<grd, blk, 0, stream>>>(hE0, 0, hE0, cE0, hE1, cE1,
                                    dec_w, dec_b, nullptr, 1);
    fused5<<<grd, blk, 0, stream>>>(hE0, 0, hE1, cE1, hX,  cE0,
                                    dec_w, dec_b, nullptr, 0);
    fused5<<<grd, blk, 0, stream>>>(hE0, 0, hX,  cE0, hE1, cE1,
                                    dec_w, dec_b, nullptr, 0);
    fused5<<<grd, blk, 0, stream>>>(hE0, 0, hE1, cE1, hX,  cE0,
                                    dec_w, dec_b, dout, 0);
}